// Round 5
// baseline (602.427 us; speedup 1.0000x reference)
//
#include <hip/hip_runtime.h>
#include <hip/hip_bf16.h>
#include <hip/hip_cooperative_groups.h>

namespace cg = cooperative_groups;

typedef __bf16 bf16x4 __attribute__((ext_vector_type(4)));
typedef __bf16 bf16x8 __attribute__((ext_vector_type(8)));
typedef float  floatx4 __attribute__((ext_vector_type(4)));

#define AS1 __attribute__((address_space(1)))
#define AS3 __attribute__((address_space(3)))

#define BM2 256
#define BN2 256
#define BK2 64

#define BARRIER() asm volatile("s_barrier" ::: "memory")

// ---------------------------------------------------------------------------
// GEMM v8 tile body: 256x256, BK=64, 8 waves (2Mx4N), 4 phases/K-tile.
// Change vs v7: fragment ds_reads are HOISTED to the HEAD of each phase
// (before setprio(1)+MFMA cluster) so the LDS-port time drains under the
// matrix-pipe burst (m201 ordering). v7 had them after the cluster ->
// phase time = MFMA + LDS serialized (measured 4875 cyc/tile vs 2060 MFMA
// floor). bfr reads stay post-cluster in P3 (WAR on bfr; a second bfr set
// would push VGPR past the 256/wave that keeps 2 waves/SIMD: 112+128acc=240).
//
// Per-tile schedule (tile kt, c=kt&1; reads at phase HEAD):
//  P0: stage A(kt+1)q1q3->sA[c^1]; read afO<-sA[c] rows+32; MFMA<0>(afE,bfr);
//      vmcnt(8) [drains A(kt)q1q3]; BARRIER
//  P1: stage B(kt+2)x4 -> sB[c];   read afE<-sA[c] rows+64; MFMA<1>(afO,bfr); BARRIER
//  P2: stage A(kt+2)q0q2->sA[c];   read afO<-sA[c] rows+96; MFMA<2>(afE,bfr);
//      vmcnt(8) [drains B(kt+1)+A(kt+1)q0q2]; BARRIER
//  P3: read afE<-sA[c^1] rows+0 (next tile, q0/q2: drained at P2);
//      MFMA<3>(afO,bfr); read bfr<-sB[c^1] (B(kt+1)); BARRIER
// Steady outstanding at tile entry = 8; vmcnt never 0 in the loop.
// ---------------------------------------------------------------------------
template<int P>
__device__ __forceinline__ void mfma_cluster(floatx4 (&acc)[8][4],
                                             const bf16x8 (&af)[2][2],
                                             const bf16x8 (&bfr)[4][2])
{
    __builtin_amdgcn_s_setprio(1);
#pragma unroll
    for (int h = 0; h < 2; ++h)
#pragma unroll
        for (int ii = 0; ii < 2; ++ii)
#pragma unroll
            for (int j = 0; j < 4; ++j)
                acc[2 * P + ii][j] = __builtin_amdgcn_mfma_f32_16x16x32_bf16(
                    af[ii][h], bfr[j][h], acc[2 * P + ii][j], 0, 0, 0);
    __builtin_amdgcn_s_setprio(0);
}

__device__ __forceinline__ void read_af(bf16x8 (&dst)[2][2], const __bf16* cA,
                                        int rowBase, int lm, int kq, int sw)
{
#pragma unroll
    for (int ii = 0; ii < 2; ++ii)
#pragma unroll
        for (int h = 0; h < 2; ++h)
            dst[ii][h] = *reinterpret_cast<const bf16x8*>(
                &cA[(rowBase + ii * 16 + lm) * BK2 + ((kq + h * 4) ^ sw) * 8]);
}

__device__ __forceinline__ void read_bf(bf16x8 (&dst)[4][2], const __bf16* cB,
                                        int wn, int lm, int kq, int sw)
{
#pragma unroll
    for (int j = 0; j < 4; ++j)
#pragma unroll
        for (int h = 0; h < 2; ++h)
            dst[j][h] = *reinterpret_cast<const bf16x8*>(
                &cB[(wn + j * 16 + lm) * BK2 + ((kq + h * 4) ^ sw) * 8]);
}

__device__ __forceinline__ void gemm_tile256(
    __bf16* sAp, __bf16* sBp,
    const __bf16* __restrict__ A, const __bf16* __restrict__ B,
    const float* __restrict__ scale, const float* __restrict__ bias,
    float* __restrict__ Out, int N, int K, int row0, int col0,
    int wave, int lane)
{
    // staging: one call = 512thr x 16B = 8KB = one 64-row quarter.
    // LDS[row][blk] = G[row][blk ^ (row&7)]  (linear dest, pre-swizzled src).
    const int sRow = lane >> 3;
    const int gBlk = (lane & 7) ^ sRow;
    const size_t aBase = (size_t)(row0 + wave * 8 + sRow) * K + gBlk * 8;
    const size_t bBase = (size_t)(col0 + wave * 8 + sRow) * K + gBlk * 8;
    const int ldsWOff = wave * 8 * BK2;

#define STAGE_A(buf, q, kt_) \
    __builtin_amdgcn_global_load_lds( \
        (const AS1 void*)(A + aBase + (size_t)(q) * 64 * K + (size_t)(kt_) * BK2), \
        (AS3 void*)(sAp + (buf) * (BM2 * BK2) + (q) * 64 * BK2 + ldsWOff), 16, 0, 0)
#define STAGE_B(buf, q, kt_) \
    __builtin_amdgcn_global_load_lds( \
        (const AS1 void*)(B + bBase + (size_t)(q) * 64 * K + (size_t)(kt_) * BK2), \
        (AS3 void*)(sBp + (buf) * (BN2 * BK2) + (q) * 64 * BK2 + ldsWOff), 16, 0, 0)

    // fragment geometry
    const int wm = (wave >> 2) * 128;
    const int wn = (wave & 3) * 64;
    const int lm = lane & 15;
    const int kq = lane >> 4;
    const int sw = lm & 7;

    floatx4 acc[8][4];
#pragma unroll
    for (int i = 0; i < 8; ++i)
#pragma unroll
        for (int j = 0; j < 4; ++j)
            acc[i][j] = (floatx4)0.0f;

    bf16x8 bfr[4][2];      // current tile's B fragments
    bf16x8 afE[2][2];      // A fragments, even phases
    bf16x8 afO[2][2];      // A fragments, odd phases
    const int nt = K / BK2;   // launcher guarantees even, >= 4

    // --- prologue. Outstanding after: [A(0)q1q3][B(1)][A(1)q0q2] = 8.
    STAGE_A(0, 0, 0); STAGE_A(0, 2, 0);
    STAGE_B(0, 0, 0); STAGE_B(0, 1, 0); STAGE_B(0, 2, 0); STAGE_B(0, 3, 0);
    STAGE_A(0, 1, 0); STAGE_A(0, 3, 0);
    STAGE_B(1, 0, 1); STAGE_B(1, 1, 1); STAGE_B(1, 2, 1); STAGE_B(1, 3, 1);
    STAGE_A(1, 0, 1); STAGE_A(1, 2, 1);
    asm volatile("s_waitcnt vmcnt(8)" ::: "memory");   // drains A(0)q0q2 + B(0)
    BARRIER();
    read_bf(bfr, sBp, wn, lm, kq, sw);
    read_af(afE, sAp, wm, lm, kq, sw);

#define TILE(c, n1, n2)                                                        \
    /* P0 */                                                                   \
    STAGE_A((c) ^ 1, 1, n1); STAGE_A((c) ^ 1, 3, n1);                          \
    read_af(afO, sAp + (c) * (BM2 * BK2), wm + 32, lm, kq, sw);                \
    mfma_cluster<0>(acc, afE, bfr);                                            \
    asm volatile("s_waitcnt vmcnt(8)" ::: "memory");                           \
    BARRIER();                                                                 \
    /* P1 */                                                                   \
    STAGE_B((c), 0, n2); STAGE_B((c), 1, n2);                                  \
    STAGE_B((c), 2, n2); STAGE_B((c), 3, n2);                                  \
    read_af(afE, sAp + (c) * (BM2 * BK2), wm + 64, lm, kq, sw);                \
    mfma_cluster<1>(acc, afO, bfr);                                            \
    BARRIER();                                                                 \
    /* P2 */                                                                   \
    STAGE_A((c), 0, n2); STAGE_A((c), 2, n2);                                  \
    read_af(afO, sAp + (c) * (BM2 * BK2), wm + 96, lm, kq, sw);                \
    mfma_cluster<2>(acc, afE, bfr);                                            \
    asm volatile("s_waitcnt vmcnt(8)" ::: "memory");                           \
    BARRIER();                                                                 \
    /* P3 */                                                                   \
    read_af(afE, sAp + ((c) ^ 1) * (BM2 * BK2), wm, lm, kq, sw);               \
    mfma_cluster<3>(acc, afO, bfr);                                            \
    read_bf(bfr, sBp + ((c) ^ 1) * (BN2 * BK2), wn, lm, kq, sw);               \
    BARRIER();

    for (int it = 0; it < nt / 2; ++it) {
        const int kt = 2 * it;
        const int e1 = kt + 1;                        // real
        const int e2 = (kt + 2 < nt) ? kt + 2 : 0;    // phantoms keep FIFO uniform
        const int o2 = (kt + 3 < nt) ? kt + 3 : 0;
        TILE(0, e1, e2)
        TILE(1, e2, o2)
    }
    asm volatile("s_waitcnt vmcnt(0)" ::: "memory");  // drain phantoms
#undef TILE
#undef STAGE_A
#undef STAGE_B

    // --- epilogue: C/D layout col=lane&15, row=(lane>>4)*4+reg (m89-verified)
#pragma unroll
    for (int j = 0; j < 4; ++j) {
        int n = col0 + wn + j * 16 + lm;
        float sc = scale[n];
        float bi = bias[n];
#pragma unroll
        for (int i = 0; i < 8; ++i) {
#pragma unroll
            for (int r = 0; r < 4; ++r) {
                int m = row0 + wm + i * 16 + kq * 4 + r;
                Out[(size_t)m * N + n] = sc * acc[i][j][r] + bi;
            }
        }
    }
}

// ---------------------------------------------------------------------------
// Fused cooperative kernel: convert (grid-stride) -> grid.sync -> persistent
// GEMM (each of 256 blocks does nTiles/256 tiles). One launch total.
// ---------------------------------------------------------------------------
__global__ __launch_bounds__(512)
void fused_coop(const float* __restrict__ xin, const int* __restrict__ win,
                const float* __restrict__ scale, const float* __restrict__ bias,
                float* __restrict__ out, __bf16* __restrict__ xb,
                __bf16* __restrict__ wb, int M, int N, int K, int nx8, int nw8)
{
    // phase 1: convert fp32->bf16 and int32->bf16
    {
        const int stride = gridDim.x * 512;
        const int total  = nx8 + nw8;
        for (int i = blockIdx.x * 512 + threadIdx.x; i < total; i += stride) {
            if (i < nx8) {
                const float4* p = reinterpret_cast<const float4*>(xin) + (size_t)i * 2;
                float4 a = p[0], b = p[1];
                bf16x8 h;
                h[0] = (__bf16)a.x; h[1] = (__bf16)a.y; h[2] = (__bf16)a.z; h[3] = (__bf16)a.w;
                h[4] = (__bf16)b.x; h[5] = (__bf16)b.y; h[6] = (__bf16)b.z; h[7] = (__bf16)b.w;
                reinterpret_cast<bf16x8*>(xb)[i] = h;
            } else {
                int j = i - nx8;
                const int4* p = reinterpret_cast<const int4*>(win) + (size_t)j * 2;
                int4 a = p[0], b = p[1];
                bf16x8 h;
                h[0] = (__bf16)(float)a.x; h[1] = (__bf16)(float)a.y;
                h[2] = (__bf16)(float)a.z; h[3] = (__bf16)(float)a.w;
                h[4] = (__bf16)(float)b.x; h[5] = (__bf16)(float)b.y;
                h[6] = (__bf16)(float)b.z; h[7] = (__bf16)(float)b.w;
                reinterpret_cast<bf16x8*>(wb)[j] = h;
            }
        }
    }
    cg::this_grid().sync();

    // phase 2: persistent GEMM
    __shared__ __bf16 sA[2 * BM2 * BK2];   // 64 KB
    __shared__ __bf16 sB[2 * BN2 * BK2];   // 64 KB
    const int wave = threadIdx.x >> 6;
    const int lane = threadIdx.x & 63;
    const int nbx = N / BN2;
    const int nTiles = (M / BM2) * nbx;
    for (int t = blockIdx.x; t < nTiles; t += gridDim.x) {
        gemm_tile256(sA, sB, xb, wb, scale, bias, out, N, K,
                     (t / nbx) * BM2, (t % nbx) * BN2, wave, lane);
    }
}

// ---------------------------------------------------------------------------
// Two-kernel fallback path (same GEMM body, classic grid).
// ---------------------------------------------------------------------------
__global__ __launch_bounds__(256)
void cvt_both8(const float* __restrict__ xin, const int* __restrict__ win,
               __bf16* __restrict__ xout, __bf16* __restrict__ wout,
               int nx8, int nw8)
{
    const int stride = gridDim.x * 256;
    const int total  = nx8 + nw8;
    for (int i = blockIdx.x * 256 + threadIdx.x; i < total; i += stride) {
        if (i < nx8) {
            const float4* p = reinterpret_cast<const float4*>(xin) + (size_t)i * 2;
            float4 a = p[0], b = p[1];
            bf16x8 h;
            h[0] = (__bf16)a.x; h[1] = (__bf16)a.y; h[2] = (__bf16)a.z; h[3] = (__bf16)a.w;
            h[4] = (__bf16)b.x; h[5] = (__bf16)b.y; h[6] = (__bf16)b.z; h[7] = (__bf16)b.w;
            reinterpret_cast<bf16x8*>(xout)[i] = h;
        } else {
            int j = i - nx8;
            const int4* p = reinterpret_cast<const int4*>(win) + (size_t)j * 2;
            int4 a = p[0], b = p[1];
            bf16x8 h;
            h[0] = (__bf16)(float)a.x; h[1] = (__bf16)(float)a.y;
            h[2] = (__bf16)(float)a.z; h[3] = (__bf16)(float)a.w;
            h[4] = (__bf16)(float)b.x; h[5] = (__bf16)(float)b.y;
            h[6] = (__bf16)(float)b.z; h[7] = (__bf16)(float)b.w;
            reinterpret_cast<bf16x8*>(wout)[j] = h;
        }
    }
}

__global__ __launch_bounds__(512)
void gemm_bf16_bt_pipe(const __bf16* __restrict__ A, const __bf16* __restrict__ B,
                       const float* __restrict__ scale, const float* __restrict__ bias,
                       float* __restrict__ Out, int M, int N, int K)
{
    __shared__ __bf16 sA[2 * BM2 * BK2];
    __shared__ __bf16 sB[2 * BN2 * BK2];
    gemm_tile256(sA, sB, A, B, scale, bias, Out, N, K,
                 blockIdx.y * BM2, blockIdx.x * BN2,
                 threadIdx.x >> 6, threadIdx.x & 63);
}

// ---------------------------------------------------------------------------
// Last-resort fallback: fused conversion in staging, no workspace needed.
// ---------------------------------------------------------------------------
#define BM 128
#define BN 128

__global__ __launch_bounds__(256)
void fp4linear_gemm(const float* __restrict__ X, const int* __restrict__ W,
                    const float* __restrict__ scale, const float* __restrict__ bias,
                    float* __restrict__ Out, int M, int N, int K)
{
    __shared__ __bf16 sA[BM * 32];
    __shared__ __bf16 sB[BN * 32];

    const int tid  = threadIdx.x;
    const int row0 = blockIdx.y * BM;
    const int col0 = blockIdx.x * BN;
    const int wave = tid >> 6;
    const int lane = tid & 63;
    const int wm = (wave >> 1) * 64;
    const int wn = (wave & 1) * 64;
    const int lm = lane & 15;
    const int kq = lane >> 4;

    floatx4 acc[4][4];
#pragma unroll
    for (int i = 0; i < 4; ++i)
#pragma unroll
        for (int j = 0; j < 4; ++j)
            acc[i][j] = (floatx4)0.0f;

    for (int k0 = 0; k0 < K; k0 += 32) {
        float4 fa[4];
        int4   ib[4];
#pragma unroll
        for (int l = 0; l < 4; ++l) {
            int idx = tid + l * 256;
            int r = idx >> 3, c4 = idx & 7;
            fa[l] = *reinterpret_cast<const float4*>(
                        &X[(size_t)(row0 + r) * K + k0 + c4 * 4]);
        }
#pragma unroll
        for (int l = 0; l < 4; ++l) {
            int idx = tid + l * 256;
            int r = idx >> 3, c4 = idx & 7;
            ib[l] = *reinterpret_cast<const int4*>(
                        &W[(size_t)(col0 + r) * K + k0 + c4 * 4]);
        }
        __syncthreads();
#pragma unroll
        for (int l = 0; l < 4; ++l) {
            int idx = tid + l * 256;
            int r = idx >> 3, c4 = idx & 7;
            bf16x4 h;
            h[0] = (__bf16)fa[l].x; h[1] = (__bf16)fa[l].y;
            h[2] = (__bf16)fa[l].z; h[3] = (__bf16)fa[l].w;
            *reinterpret_cast<bf16x4*>(&sA[r * 32 + c4 * 4]) = h;
        }
#pragma unroll
        for (int l = 0; l < 4; ++l) {
            int idx = tid + l * 256;
            int r = idx >> 3, c4 = idx & 7;
            bf16x4 h;
            h[0] = (__bf16)(float)ib[l].x; h[1] = (__bf16)(float)ib[l].y;
            h[2] = (__bf16)(float)ib[l].z; h[3] = (__bf16)(float)ib[l].w;
            *reinterpret_cast<bf16x4*>(&sB[r * 32 + c4 * 4]) = h;
        }
        __syncthreads();

        bf16x8 af[4], bfr[4];
#pragma unroll
        for (int i = 0; i < 4; ++i)
            af[i] = *reinterpret_cast<const bf16x8*>(
                        &sA[(wm + i * 16 + lm) * 32 + kq * 8]);
#pragma unroll
        for (int j = 0; j < 4; ++j)
            bfr[j] = *reinterpret_cast<const bf16x8*>(
                        &sB[(wn + j * 16 + lm) * 32 + kq * 8]);
#pragma unroll
        for (int i = 0; i < 4; ++i)
#pragma unroll
            for (int j = 0; j < 4; ++j)
                acc[i][j] = __builtin_amdgcn_mfma_f32_16x16x32_bf16(
                                af[i], bfr[j], acc[i][j], 0, 0, 0);
    }

#pragma unroll
    for (int j = 0; j < 4; ++j) {
        int n = col0 + wn + j * 16 + lm;
        float sc = scale[n];
        float bi = bias[n];
#pragma unroll
        for (int i = 0; i < 4; ++i) {
#pragma unroll
            for (int r = 0; r < 4; ++r) {
                int m = row0 + wm + i * 16 + kq * 4 + r;
                Out[(size_t)m * N + n] = sc * acc[i][j][r] + bi;
            }
        }
    }
}

extern "C" void kernel_launch(void* const* d_in, const int* in_sizes, int n_in,
                              void* d_out, int out_size, void* d_ws, size_t ws_size,
                              hipStream_t stream) {
    const float* x     = (const float*)d_in[0];
    const int*   wq    = (const int*)d_in[1];
    const float* scale = (const float*)d_in[2];
    const float* bias  = (const float*)d_in[3];
    float* out = (float*)d_out;

    const int N = in_sizes[2];            // OUT = 4096
    const int K = in_sizes[1] / N;        // IN  = 4096
    const int M = in_sizes[0] / K;        // B*S = 8192

    const size_t xElems = (size_t)M * K;
    const size_t wElems = (size_t)N * K;
    const size_t need   = (xElems + wElems) * sizeof(__bf16);

    const bool cvt_ok = (ws_size >= need) && (xElems % 8 == 0) && (wElems % 8 == 0);
    const int  nt     = K / BK2;
    const bool gemm_ok = (M % BM2 == 0) && (N % BN2 == 0) && (K % BK2 == 0) &&
                         (nt % 2 == 0) && (nt >= 4);

    if (cvt_ok && gemm_ok) {
        __bf16* xb = (__bf16*)d_ws;
        __bf16* wb = xb + xElems;
        int nx8 = (int)(xElems / 8);
        int nw8 = (int)(wElems / 8);
        int nTiles = (M / BM2) * (N / BN2);
        int coopBlocks = nTiles < 256 ? nTiles : 256;

        void* args[] = { (void*)&x, (void*)&wq, (void*)&scale, (void*)&bias,
                         (void*)&out, (void*)&xb, (void*)&wb,
                         (void*)&M, (void*)&N, (void*)&K,
                         (void*)&nx8, (void*)&nw8 };
        hipError_t e = hipLaunchCooperativeKernel((void*)fused_coop,
                                                  dim3(coopBlocks), dim3(512),
                                                  args, 0, stream);
        if (e == hipSuccess) return;

        // fallback: two-kernel path (same GEMM body)
        int total = nx8 + nw8;
        int cvtBlocks = (total + 255) / 256;
        if (cvtBlocks > 2048) cvtBlocks = 2048;
        hipLaunchKernelGGL(cvt_both8, dim3(cvtBlocks), dim3(256), 0, stream,
                           x, wq, xb, wb, nx8, nw8);
        hipLaunchKernelGGL(gemm_bf16_bt_pipe, dim3(N / BN2, M / BM2), dim3(512),
                           0, stream, xb, wb, scale, bias, out, M, N, K);
        return;
    }

    hipLaunchKernelGGL(fp4linear_gemm, dim3(N / BN, M / BM), dim3(256), 0, stream,
                       x, wq, scale, bias, out, M, N, K);
}

// Round 6
// 530.327 us; speedup vs baseline: 1.1360x; 1.1360x over previous
//
#include <hip/hip_runtime.h>
#include <hip/hip_bf16.h>

typedef __bf16 bf16x4 __attribute__((ext_vector_type(4)));
typedef __bf16 bf16x8 __attribute__((ext_vector_type(8)));
typedef float  floatx4 __attribute__((ext_vector_type(4)));

#define AS1 __attribute__((address_space(1)))
#define AS3 __attribute__((address_space(3)))

#define BM2 256
#define BN2 256
#define BK2 64

#define BARRIER() asm volatile("s_barrier" ::: "memory")

// ---------------------------------------------------------------------------
// Prepass: fp32->bf16 (x) and int32->bf16 (wq), one launch.
// Grid-stride, <=2048 blocks, 8 elems/thread. Measured ~65us (near its
// ~48us roofline) — not the lever; total-minus-dispatch overhead is ~180us
// fixed (proven by round-5 single-dispatch coop experiment).
// ---------------------------------------------------------------------------
__global__ __launch_bounds__(256)
void cvt_both8(const float* __restrict__ xin, const int* __restrict__ win,
               __bf16* __restrict__ xout, __bf16* __restrict__ wout,
               int nx8, int nw8)
{
    const int stride = gridDim.x * 256;
    const int total  = nx8 + nw8;
    for (int i = blockIdx.x * 256 + threadIdx.x; i < total; i += stride) {
        if (i < nx8) {
            const float4* p = reinterpret_cast<const float4*>(xin) + (size_t)i * 2;
            float4 a = p[0], b = p[1];
            bf16x8 h;
            h[0] = (__bf16)a.x; h[1] = (__bf16)a.y; h[2] = (__bf16)a.z; h[3] = (__bf16)a.w;
            h[4] = (__bf16)b.x; h[5] = (__bf16)b.y; h[6] = (__bf16)b.z; h[7] = (__bf16)b.w;
            reinterpret_cast<bf16x8*>(xout)[i] = h;
        } else {
            int j = i - nx8;
            const int4* p = reinterpret_cast<const int4*>(win) + (size_t)j * 2;
            int4 a = p[0], b = p[1];
            bf16x8 h;
            h[0] = (__bf16)(float)a.x; h[1] = (__bf16)(float)a.y;
            h[2] = (__bf16)(float)a.z; h[3] = (__bf16)(float)a.w;
            h[4] = (__bf16)(float)b.x; h[5] = (__bf16)(float)b.y;
            h[6] = (__bf16)(float)b.z; h[7] = (__bf16)(float)b.w;
            reinterpret_cast<bf16x8*>(wout)[j] = h;
        }
    }
}

// ---------------------------------------------------------------------------
// GEMM v8 (two-kernel config — first clean measurement of the hoisted-read
// body): 256x256, BK=64, 8 waves (2Mx4N), 4 phases/K-tile.
// Fragment ds_reads at the HEAD of each phase (before setprio(1)+MFMA) so
// LDS-port time drains under the matrix-pipe burst. bfr reads stay
// post-cluster in P3 (WAR on bfr; second set would blow the 2-waves/SIMD
// VGPR budget).
//
// Per-tile schedule (tile kt, c=kt&1):
//  P0: stage A(kt+1)q1q3->sA[c^1]; read afO<-sA[c] rows+32; MFMA<0>(afE,bfr);
//      vmcnt(8) [drains A(kt)q1q3]; BARRIER
//  P1: stage B(kt+2)x4 -> sB[c];   read afE<-sA[c] rows+64; MFMA<1>(afO,bfr); BARRIER
//  P2: stage A(kt+2)q0q2->sA[c];   read afO<-sA[c] rows+96; MFMA<2>(afE,bfr);
//      vmcnt(8) [drains B(kt+1)+A(kt+1)q0q2]; BARRIER
//  P3: read afE<-sA[c^1] rows+0 (q0/q2 drained at P2); MFMA<3>(afO,bfr);
//      read bfr<-sB[c^1] (B(kt+1)); BARRIER
// Steady outstanding at tile entry = 8; vmcnt never 0 in the loop.
// ---------------------------------------------------------------------------
template<int P>
__device__ __forceinline__ void mfma_cluster(floatx4 (&acc)[8][4],
                                             const bf16x8 (&af)[2][2],
                                             const bf16x8 (&bfr)[4][2])
{
    __builtin_amdgcn_s_setprio(1);
#pragma unroll
    for (int h = 0; h < 2; ++h)
#pragma unroll
        for (int ii = 0; ii < 2; ++ii)
#pragma unroll
            for (int j = 0; j < 4; ++j)
                acc[2 * P + ii][j] = __builtin_amdgcn_mfma_f32_16x16x32_bf16(
                    af[ii][h], bfr[j][h], acc[2 * P + ii][j], 0, 0, 0);
    __builtin_amdgcn_s_setprio(0);
}

__device__ __forceinline__ void read_af(bf16x8 (&dst)[2][2], const __bf16* cA,
                                        int rowBase, int lm, int kq, int sw)
{
#pragma unroll
    for (int ii = 0; ii < 2; ++ii)
#pragma unroll
        for (int h = 0; h < 2; ++h)
            dst[ii][h] = *reinterpret_cast<const bf16x8*>(
                &cA[(rowBase + ii * 16 + lm) * BK2 + ((kq + h * 4) ^ sw) * 8]);
}

__device__ __forceinline__ void read_bf(bf16x8 (&dst)[4][2], const __bf16* cB,
                                        int wn, int lm, int kq, int sw)
{
#pragma unroll
    for (int j = 0; j < 4; ++j)
#pragma unroll
        for (int h = 0; h < 2; ++h)
            dst[j][h] = *reinterpret_cast<const bf16x8*>(
                &cB[(wn + j * 16 + lm) * BK2 + ((kq + h * 4) ^ sw) * 8]);
}

__global__ __launch_bounds__(512)
void gemm_bf16_bt_pipe(const __bf16* __restrict__ A, const __bf16* __restrict__ B,
                       const float* __restrict__ scale, const float* __restrict__ bias,
                       float* __restrict__ Out, int M, int N, int K)
{
    __shared__ __bf16 sA[2][BM2 * BK2];   // 64 KB
    __shared__ __bf16 sB[2][BN2 * BK2];   // 64 KB

    const int tid  = threadIdx.x;
    const int wave = tid >> 6;
    const int lane = tid & 63;
    const int row0 = blockIdx.y * BM2;
    const int col0 = blockIdx.x * BN2;

    // staging: one call = 512thr x 16B = 8KB = one 64-row quarter.
    // LDS[row][blk] = G[row][blk ^ (row&7)]  (linear dest, pre-swizzled src).
    const int sRow = lane >> 3;
    const int gBlk = (lane & 7) ^ sRow;
    const size_t aBase = (size_t)(row0 + wave * 8 + sRow) * K + gBlk * 8;
    const size_t bBase = (size_t)(col0 + wave * 8 + sRow) * K + gBlk * 8;
    const int ldsWOff = wave * 8 * BK2;

#define STAGE_A(buf, q, kt_) \
    __builtin_amdgcn_global_load_lds( \
        (const AS1 void*)(A + aBase + (size_t)(q) * 64 * K + (size_t)(kt_) * BK2), \
        (AS3 void*)&sA[(buf)][(q) * 64 * BK2 + ldsWOff], 16, 0, 0)
#define STAGE_B(buf, q, kt_) \
    __builtin_amdgcn_global_load_lds( \
        (const AS1 void*)(B + bBase + (size_t)(q) * 64 * K + (size_t)(kt_) * BK2), \
        (AS3 void*)&sB[(buf)][(q) * 64 * BK2 + ldsWOff], 16, 0, 0)

    // fragment geometry
    const int wm = (wave >> 2) * 128;
    const int wn = (wave & 3) * 64;
    const int lm = lane & 15;
    const int kq = lane >> 4;
    const int sw = lm & 7;

    floatx4 acc[8][4];
#pragma unroll
    for (int i = 0; i < 8; ++i)
#pragma unroll
        for (int j = 0; j < 4; ++j)
            acc[i][j] = (floatx4)0.0f;

    bf16x8 bfr[4][2];      // current tile's B fragments
    bf16x8 afE[2][2];      // A fragments, even phases
    bf16x8 afO[2][2];      // A fragments, odd phases
    const int nt = K / BK2;   // launcher guarantees even, >= 4

    // --- prologue. Outstanding after: [A(0)q1q3][B(1)][A(1)q0q2] = 8.
    STAGE_A(0, 0, 0); STAGE_A(0, 2, 0);
    STAGE_B(0, 0, 0); STAGE_B(0, 1, 0); STAGE_B(0, 2, 0); STAGE_B(0, 3, 0);
    STAGE_A(0, 1, 0); STAGE_A(0, 3, 0);
    STAGE_B(1, 0, 1); STAGE_B(1, 1, 1); STAGE_B(1, 2, 1); STAGE_B(1, 3, 1);
    STAGE_A(1, 0, 1); STAGE_A(1, 2, 1);
    asm volatile("s_waitcnt vmcnt(8)" ::: "memory");   // drains A(0)q0q2 + B(0)
    BARRIER();
    read_bf(bfr, sB[0], wn, lm, kq, sw);
    read_af(afE, sA[0], wm, lm, kq, sw);

#define TILE(c, n1, n2)                                                        \
    /* P0 */                                                                   \
    STAGE_A((c) ^ 1, 1, n1); STAGE_A((c) ^ 1, 3, n1);                          \
    read_af(afO, sA[(c)], wm + 32, lm, kq, sw);                                \
    mfma_cluster<0>(acc, afE, bfr);                                            \
    asm volatile("s_waitcnt vmcnt(8)" ::: "memory");                           \
    BARRIER();                                                                 \
    /* P1 */                                                                   \
    STAGE_B((c), 0, n2); STAGE_B((c), 1, n2);                                  \
    STAGE_B((c), 2, n2); STAGE_B((c), 3, n2);                                  \
    read_af(afE, sA[(c)], wm + 64, lm, kq, sw);                                \
    mfma_cluster<1>(acc, afO, bfr);                                            \
    BARRIER();                                                                 \
    /* P2 */                                                                   \
    STAGE_A((c), 0, n2); STAGE_A((c), 2, n2);                                  \
    read_af(afO, sA[(c)], wm + 96, lm, kq, sw);                                \
    mfma_cluster<2>(acc, afE, bfr);                                            \
    asm volatile("s_waitcnt vmcnt(8)" ::: "memory");                           \
    BARRIER();                                                                 \
    /* P3 */                                                                   \
    read_af(afE, sA[(c) ^ 1], wm, lm, kq, sw);                                 \
    mfma_cluster<3>(acc, afO, bfr);                                            \
    read_bf(bfr, sB[(c) ^ 1], wn, lm, kq, sw);                                 \
    BARRIER();

    for (int it = 0; it < nt / 2; ++it) {
        const int kt = 2 * it;
        const int e1 = kt + 1;                        // real
        const int e2 = (kt + 2 < nt) ? kt + 2 : 0;    // phantoms keep FIFO uniform
        const int o2 = (kt + 3 < nt) ? kt + 3 : 0;
        TILE(0, e1, e2)
        TILE(1, e2, o2)
    }
    asm volatile("s_waitcnt vmcnt(0)" ::: "memory");  // drain phantoms
#undef TILE
#undef STAGE_A
#undef STAGE_B

    // --- epilogue: C/D layout col=lane&15, row=(lane>>4)*4+reg (m89-verified)
#pragma unroll
    for (int j = 0; j < 4; ++j) {
        int n = col0 + wn + j * 16 + lm;
        float sc = scale[n];
        float bi = bias[n];
#pragma unroll
        for (int i = 0; i < 8; ++i) {
#pragma unroll
            for (int r = 0; r < 4; ++r) {
                int m = row0 + wm + i * 16 + kq * 4 + r;
                Out[(size_t)m * N + n] = sc * acc[i][j][r] + bi;
            }
        }
    }
}

// ---------------------------------------------------------------------------
// Last-resort fallback: fused conversion in staging, no workspace needed.
// ---------------------------------------------------------------------------
#define BM 128
#define BN 128

__global__ __launch_bounds__(256)
void fp4linear_gemm(const float* __restrict__ X, const int* __restrict__ W,
                    const float* __restrict__ scale, const float* __restrict__ bias,
                    float* __restrict__ Out, int M, int N, int K)
{
    __shared__ __bf16 sA[BM * 32];
    __shared__ __bf16 sB[BN * 32];

    const int tid  = threadIdx.x;
    const int row0 = blockIdx.y * BM;
    const int col0 = blockIdx.x * BN;
    const int wave = tid >> 6;
    const int lane = tid & 63;
    const int wm = (wave >> 1) * 64;
    const int wn = (wave & 1) * 64;
    const int lm = lane & 15;
    const int kq = lane >> 4;

    floatx4 acc[4][4];
#pragma unroll
    for (int i = 0; i < 4; ++i)
#pragma unroll
        for (int j = 0; j < 4; ++j)
            acc[i][j] = (floatx4)0.0f;

    for (int k0 = 0; k0 < K; k0 += 32) {
        float4 fa[4];
        int4   ib[4];
#pragma unroll
        for (int l = 0; l < 4; ++l) {
            int idx = tid + l * 256;
            int r = idx >> 3, c4 = idx & 7;
            fa[l] = *reinterpret_cast<const float4*>(
                        &X[(size_t)(row0 + r) * K + k0 + c4 * 4]);
        }
#pragma unroll
        for (int l = 0; l < 4; ++l) {
            int idx = tid + l * 256;
            int r = idx >> 3, c4 = idx & 7;
            ib[l] = *reinterpret_cast<const int4*>(
                        &W[(size_t)(col0 + r) * K + k0 + c4 * 4]);
        }
        __syncthreads();
#pragma unroll
        for (int l = 0; l < 4; ++l) {
            int idx = tid + l * 256;
            int r = idx >> 3, c4 = idx & 7;
            bf16x4 h;
            h[0] = (__bf16)fa[l].x; h[1] = (__bf16)fa[l].y;
            h[2] = (__bf16)fa[l].z; h[3] = (__bf16)fa[l].w;
            *reinterpret_cast<bf16x4*>(&sA[r * 32 + c4 * 4]) = h;
        }
#pragma unroll
        for (int l = 0; l < 4; ++l) {
            int idx = tid + l * 256;
            int r = idx >> 3, c4 = idx & 7;
            bf16x4 h;
            h[0] = (__bf16)(float)ib[l].x; h[1] = (__bf16)(float)ib[l].y;
            h[2] = (__bf16)(float)ib[l].z; h[3] = (__bf16)(float)ib[l].w;
            *reinterpret_cast<bf16x4*>(&sB[r * 32 + c4 * 4]) = h;
        }
        __syncthreads();

        bf16x8 af[4], bfr[4];
#pragma unroll
        for (int i = 0; i < 4; ++i)
            af[i] = *reinterpret_cast<const bf16x8*>(
                        &sA[(wm + i * 16 + lm) * 32 + kq * 8]);
#pragma unroll
        for (int j = 0; j < 4; ++j)
            bfr[j] = *reinterpret_cast<const bf16x8*>(
                        &sB[(wn + j * 16 + lm) * 32 + kq * 8]);
#pragma unroll
        for (int i = 0; i < 4; ++i)
#pragma unroll
            for (int j = 0; j < 4; ++j)
                acc[i][j] = __builtin_amdgcn_mfma_f32_16x16x32_bf16(
                                af[i], bfr[j], acc[i][j], 0, 0, 0);
    }

#pragma unroll
    for (int j = 0; j < 4; ++j) {
        int n = col0 + wn + j * 16 + lm;
        float sc = scale[n];
        float bi = bias[n];
#pragma unroll
        for (int i = 0; i < 4; ++i) {
#pragma unroll
            for (int r = 0; r < 4; ++r) {
                int m = row0 + wm + i * 16 + kq * 4 + r;
                Out[(size_t)m * N + n] = sc * acc[i][j][r] + bi;
            }
        }
    }
}

extern "C" void kernel_launch(void* const* d_in, const int* in_sizes, int n_in,
                              void* d_out, int out_size, void* d_ws, size_t ws_size,
                              hipStream_t stream) {
    const float* x     = (const float*)d_in[0];
    const int*   wq    = (const int*)d_in[1];
    const float* scale = (const float*)d_in[2];
    const float* bias  = (const float*)d_in[3];
    float* out = (float*)d_out;

    const int N = in_sizes[2];            // OUT = 4096
    const int K = in_sizes[1] / N;        // IN  = 4096
    const int M = in_sizes[0] / K;        // B*S = 8192

    const size_t xElems = (size_t)M * K;
    const size_t wElems = (size_t)N * K;
    const size_t need   = (xElems + wElems) * sizeof(__bf16);

    const bool cvt_ok = (ws_size >= need) && (xElems % 8 == 0) && (wElems % 8 == 0);
    const int  nt     = K / BK2;
    const bool gemm_ok = (M % BM2 == 0) && (N % BN2 == 0) && (K % BK2 == 0) &&
                         (nt % 2 == 0) && (nt >= 4);

    if (cvt_ok && gemm_ok) {
        __bf16* xb = (__bf16*)d_ws;
        __bf16* wb = xb + xElems;
        int nx8 = (int)(xElems / 8);
        int nw8 = (int)(wElems / 8);
        int total = nx8 + nw8;
        int cvtBlocks = (total + 255) / 256;
        if (cvtBlocks > 2048) cvtBlocks = 2048;
        hipLaunchKernelGGL(cvt_both8, dim3(cvtBlocks), dim3(256), 0, stream,
                           x, wq, xb, wb, nx8, nw8);
        hipLaunchKernelGGL(gemm_bf16_bt_pipe, dim3(N / BN2, M / BM2), dim3(512),
                           0, stream, xb, wb, scale, bias, out, M, N, K);
        return;
    }

    hipLaunchKernelGGL(fp4linear_gemm, dim3(N / BN, M / BM), dim3(256), 0, stream,
                       x, wq, scale, bias, out, M, N, K);
}

// Round 7
// 508.509 us; speedup vs baseline: 1.1847x; 1.0429x over previous
//
#include <hip/hip_runtime.h>
#include <hip/hip_bf16.h>

typedef __bf16 bf16x4 __attribute__((ext_vector_type(4)));
typedef __bf16 bf16x8 __attribute__((ext_vector_type(8)));
typedef float  floatx4 __attribute__((ext_vector_type(4)));

#define AS1 __attribute__((address_space(1)))
#define AS3 __attribute__((address_space(3)))

#define BM2 256
#define BN2 256
#define BK2 64
#define HALF (128 * 64)      // elems per half-tile (128 rows x 64 cols)
#define ABUF (2 * HALF)      // elems per double-buffer slot (2 halves)

#define BARRIER() asm volatile("s_barrier" ::: "memory")

// ---------------------------------------------------------------------------
// Prepass: fp32->bf16 (x) and int32->bf16 (wq). Grid-stride, <=2048 blocks,
// 8 elems/thread. ~65us, near its ~48us roofline; total-minus-dispatch
// overhead is ~180us fixed (proven by round-5 single-dispatch experiment).
// ---------------------------------------------------------------------------
__global__ __launch_bounds__(256)
void cvt_both8(const float* __restrict__ xin, const int* __restrict__ win,
               __bf16* __restrict__ xout, __bf16* __restrict__ wout,
               int nx8, int nw8)
{
    const int stride = gridDim.x * 256;
    const int total  = nx8 + nw8;
    for (int i = blockIdx.x * 256 + threadIdx.x; i < total; i += stride) {
        if (i < nx8) {
            const float4* p = reinterpret_cast<const float4*>(xin) + (size_t)i * 2;
            float4 a = p[0], b = p[1];
            bf16x8 h;
            h[0] = (__bf16)a.x; h[1] = (__bf16)a.y; h[2] = (__bf16)a.z; h[3] = (__bf16)a.w;
            h[4] = (__bf16)b.x; h[5] = (__bf16)b.y; h[6] = (__bf16)b.z; h[7] = (__bf16)b.w;
            reinterpret_cast<bf16x8*>(xout)[i] = h;
        } else {
            int j = i - nx8;
            const int4* p = reinterpret_cast<const int4*>(win) + (size_t)j * 2;
            int4 a = p[0], b = p[1];
            bf16x8 h;
            h[0] = (__bf16)(float)a.x; h[1] = (__bf16)(float)a.y;
            h[2] = (__bf16)(float)a.z; h[3] = (__bf16)(float)a.w;
            h[4] = (__bf16)(float)b.x; h[5] = (__bf16)(float)b.y;
            h[6] = (__bf16)(float)b.z; h[7] = (__bf16)(float)b.w;
            reinterpret_cast<bf16x8*>(wout)[j] = h;
        }
    }
}

// ---------------------------------------------------------------------------
// GEMM v9 — literal m201 8-phase skeleton. 256x256, BK=64, 8 waves (2Mx4N).
// Phase = { ds_reads ; stage (2 gload_lds) ; s_barrier ; [sched_barrier]
//           setprio(1) ; 16 MFMA ; setprio(0) ; [sched_barrier]
//           [vmcnt(4) at P4/P8 only] ; s_barrier }
// Reads and their consuming MFMAs are in the SAME phase, split by barrier #1
// (read latency drains across the barrier; two-barrier cadence staggers the
// 2 waves/SIMD into load-issuing vs MFMA roles -> setprio has work to do).
// B read once per K-tile (8 ds_reads at P1/P5, held in regs 4 phases);
// A 4 ds_reads per phase (one C-quadrant). Stage spread 1 half-tile/phase:
//   P1: A(kt+1)h0->buf1  P2: A(kt+1)h1->buf1  P3: B(kt+2)h0->buf0
//   P4: B(kt+2)h1->buf0  P5: A(kt+2)h0->buf0  P6: A(kt+2)h1->buf0
//   P7: B(kt+3)h0->buf1  P8: B(kt+3)h1->buf1
// Liveness (verified): every overwritten region's readers finished >=1
// barrier before the stage issue. vmcnt(4) at P4 drains through A(kt+1)
// (needed at P5-head) keeping P3,P4; at P8 drains through A(kt+2) (needed
// next P1) keeping P7,P8. Steady FIFO at each wait = 12 -> keep 4.
// sched_barrier(0) after barrier #1 pins MFMA below the wait (rule #18);
// after the cluster pins it above barrier #2.
// ---------------------------------------------------------------------------
template<int Q>
__device__ __forceinline__ void mfma16(floatx4 (&acc)[8][4],
                                       const bf16x8 (&af)[2][2],
                                       const bf16x8 (&bfr)[4][2])
{
#pragma unroll
    for (int h = 0; h < 2; ++h)
#pragma unroll
        for (int ii = 0; ii < 2; ++ii)
#pragma unroll
            for (int j = 0; j < 4; ++j)
                acc[2 * Q + ii][j] = __builtin_amdgcn_mfma_f32_16x16x32_bf16(
                    af[ii][h], bfr[j][h], acc[2 * Q + ii][j], 0, 0, 0);
}

// read A fragments for quadrant Q from a half-tile base (rows within half)
__device__ __forceinline__ void read_afH(bf16x8 (&dst)[2][2], const __bf16* p,
                                         int rowBase, int lm, int kq, int sw)
{
#pragma unroll
    for (int ii = 0; ii < 2; ++ii)
#pragma unroll
        for (int h = 0; h < 2; ++h)
            dst[ii][h] = *reinterpret_cast<const bf16x8*>(
                &p[(rowBase + ii * 16 + lm) * 64 + ((kq + h * 4) ^ sw) * 8]);
}

// read all 8 B fragments (4 n-frags x 2 k-halves) from a half-tile base
__device__ __forceinline__ void read_bfH(bf16x8 (&dst)[4][2], const __bf16* p,
                                         int wnh, int lm, int kq, int sw)
{
#pragma unroll
    for (int j = 0; j < 4; ++j)
#pragma unroll
        for (int h = 0; h < 2; ++h)
            dst[j][h] = *reinterpret_cast<const bf16x8*>(
                &p[(wnh + j * 16 + lm) * 64 + ((kq + h * 4) ^ sw) * 8]);
}

__global__ __launch_bounds__(512)
void gemm_bf16_bt_8ph(const __bf16* __restrict__ A, const __bf16* __restrict__ B,
                      const float* __restrict__ scale, const float* __restrict__ bias,
                      float* __restrict__ Out, int M, int N, int K)
{
    __shared__ __bf16 sA[2 * ABUF];   // 64 KB: [dbuf][half][128r x 64c]
    __shared__ __bf16 sB[2 * ABUF];   // 64 KB

    const int tid  = threadIdx.x;
    const int wave = tid >> 6;
    const int lane = tid & 63;
    const int row0 = blockIdx.y * BM2;
    const int col0 = blockIdx.x * BN2;

    // staging: one gload_lds = 512thr x 16B = 8KB = 64 rows. Half = 2 calls.
    // LDS[row][blk] = G[row][blk ^ (row&7)] (linear dest, pre-swizzled src).
    const int sRow = lane >> 3;
    const int gBlk = (lane & 7) ^ sRow;
    const size_t aBase = (size_t)(row0 + wave * 8 + sRow) * K + gBlk * 8;
    const size_t bBase = (size_t)(col0 + wave * 8 + sRow) * K + gBlk * 8;
    const int dOff = wave * 8 * 64;   // wave-uniform dest offset in a 64-row chunk

#define STG_A(buf, h, sub, kt_) \
    __builtin_amdgcn_global_load_lds( \
        (const AS1 void*)(A + aBase + (size_t)((h) * 128 + (sub) * 64) * K + (size_t)(kt_) * BK2), \
        (AS3 void*)(sA + (buf) * ABUF + (h) * HALF + (sub) * 64 * 64 + dOff), 16, 0, 0)
#define STG_B(buf, h, sub, kt_) \
    __builtin_amdgcn_global_load_lds( \
        (const AS1 void*)(B + bBase + (size_t)((h) * 128 + (sub) * 64) * K + (size_t)(kt_) * BK2), \
        (AS3 void*)(sB + (buf) * ABUF + (h) * HALF + (sub) * 64 * 64 + dOff), 16, 0, 0)
#define STGH_A(buf, h, kt_) do { STG_A(buf, h, 0, kt_); STG_A(buf, h, 1, kt_); } while (0)
#define STGH_B(buf, h, kt_) do { STG_B(buf, h, 0, kt_); STG_B(buf, h, 1, kt_); } while (0)

    // fragment geometry: wave -> (wm, wn); each wave touches ONE A-half, ONE B-half
    const int hA  = wave >> 2;            // wm = hA*128
    const int hB  = (wave & 3) >> 1;      // wn = (wave&3)*64
    const int wnh = (wave & 1) * 64;      // row base of wn within its half
    const int lm  = lane & 15;
    const int kq  = lane >> 4;
    const int sw  = lm & 7;

    const __bf16* aH[2] = { sA + hA * HALF, sA + ABUF + hA * HALF };
    const __bf16* bH[2] = { sB + hB * HALF, sB + ABUF + hB * HALF };

    floatx4 acc[8][4];
#pragma unroll
    for (int i = 0; i < 8; ++i)
#pragma unroll
        for (int j = 0; j < 4; ++j)
            acc[i][j] = (floatx4)0.0f;

    bf16x8 bfr[4][2];   // current K-tile's B fragments (read once per K-tile)
    bf16x8 af[2][2];    // current quadrant's A fragments
    const int nt = K / BK2;   // launcher guarantees even, >= 4

    // --- prologue: B(0), A(0) -> buf0; B(1) -> buf1. Drain all but B(1).
    STGH_B(0, 0, 0); STGH_B(0, 1, 0);
    STGH_A(0, 0, 0); STGH_A(0, 1, 0);
    STGH_B(1, 0, 1); STGH_B(1, 1, 1);
    asm volatile("s_waitcnt vmcnt(4)" ::: "memory");
    BARRIER();

#define PH(Q, c, DOB, STAGE, DOVM)                                             \
    do {                                                                       \
        if (DOB) read_bfH(bfr, bH[c], wnh, lm, kq, sw);                        \
        read_afH(af, aH[c], (Q) * 32, lm, kq, sw);                             \
        STAGE;                                                                 \
        BARRIER();                                                             \
        __builtin_amdgcn_sched_barrier(0);                                     \
        __builtin_amdgcn_s_setprio(1);                                         \
        mfma16<Q>(acc, af, bfr);                                               \
        __builtin_amdgcn_s_setprio(0);                                         \
        __builtin_amdgcn_sched_barrier(0);                                     \
        if (DOVM) asm volatile("s_waitcnt vmcnt(4)" ::: "memory");             \
        BARRIER();                                                             \
    } while (0)

    for (int it = 0; it < nt / 2; ++it) {
        const int kt = 2 * it;
        const int e1 = kt + 1;                        // always real
        const int e2 = (kt + 2 < nt) ? kt + 2 : 0;    // phantoms keep FIFO uniform;
        const int e3 = (kt + 3 < nt) ? kt + 3 : 0;    // writes land in dead regions

        PH(0, 0, true,  STGH_A(1, 0, e1), false);     // P1
        PH(1, 0, false, STGH_A(1, 1, e1), false);     // P2
        PH(2, 0, false, STGH_B(0, 0, e2), false);     // P3
        PH(3, 0, false, STGH_B(0, 1, e2), true );     // P4  vmcnt(4)
        PH(0, 1, true,  STGH_A(0, 0, e2), false);     // P5
        PH(1, 1, false, STGH_A(0, 1, e2), false);     // P6
        PH(2, 1, false, STGH_B(1, 0, e3), false);     // P7
        PH(3, 1, false, STGH_B(1, 1, e3), true );     // P8  vmcnt(4)
    }
    asm volatile("s_waitcnt vmcnt(0)" ::: "memory");  // drain phantoms
#undef PH
#undef STGH_A
#undef STGH_B
#undef STG_A
#undef STG_B

    // --- epilogue: C/D layout col=lane&15, row=(lane>>4)*4+reg (m89-verified)
    const int wm = hA * 128;
    const int wn = (wave & 3) * 64;
#pragma unroll
    for (int j = 0; j < 4; ++j) {
        int n = col0 + wn + j * 16 + lm;
        float sc = scale[n];
        float bi = bias[n];
#pragma unroll
        for (int i = 0; i < 8; ++i) {
#pragma unroll
            for (int r = 0; r < 4; ++r) {
                int m = row0 + wm + i * 16 + kq * 4 + r;
                Out[(size_t)m * N + n] = sc * acc[i][j][r] + bi;
            }
        }
    }
}

// ---------------------------------------------------------------------------
// Last-resort fallback: fused conversion in staging, no workspace needed.
// ---------------------------------------------------------------------------
#define BM 128
#define BN 128

__global__ __launch_bounds__(256)
void fp4linear_gemm(const float* __restrict__ X, const int* __restrict__ W,
                    const float* __restrict__ scale, const float* __restrict__ bias,
                    float* __restrict__ Out, int M, int N, int K)
{
    __shared__ __bf16 sA[BM * 32];
    __shared__ __bf16 sB[BN * 32];

    const int tid  = threadIdx.x;
    const int row0 = blockIdx.y * BM;
    const int col0 = blockIdx.x * BN;
    const int wave = tid >> 6;
    const int lane = tid & 63;
    const int wm = (wave >> 1) * 64;
    const int wn = (wave & 1) * 64;
    const int lm = lane & 15;
    const int kq = lane >> 4;

    floatx4 acc[4][4];
#pragma unroll
    for (int i = 0; i < 4; ++i)
#pragma unroll
        for (int j = 0; j < 4; ++j)
            acc[i][j] = (floatx4)0.0f;

    for (int k0 = 0; k0 < K; k0 += 32) {
        float4 fa[4];
        int4   ib[4];
#pragma unroll
        for (int l = 0; l < 4; ++l) {
            int idx = tid + l * 256;
            int r = idx >> 3, c4 = idx & 7;
            fa[l] = *reinterpret_cast<const float4*>(
                        &X[(size_t)(row0 + r) * K + k0 + c4 * 4]);
        }
#pragma unroll
        for (int l = 0; l < 4; ++l) {
            int idx = tid + l * 256;
            int r = idx >> 3, c4 = idx & 7;
            ib[l] = *reinterpret_cast<const int4*>(
                        &W[(size_t)(col0 + r) * K + k0 + c4 * 4]);
        }
        __syncthreads();
#pragma unroll
        for (int l = 0; l < 4; ++l) {
            int idx = tid + l * 256;
            int r = idx >> 3, c4 = idx & 7;
            bf16x4 h;
            h[0] = (__bf16)fa[l].x; h[1] = (__bf16)fa[l].y;
            h[2] = (__bf16)fa[l].z; h[3] = (__bf16)fa[l].w;
            *reinterpret_cast<bf16x4*>(&sA[r * 32 + c4 * 4]) = h;
        }
#pragma unroll
        for (int l = 0; l < 4; ++l) {
            int idx = tid + l * 256;
            int r = idx >> 3, c4 = idx & 7;
            bf16x4 h;
            h[0] = (__bf16)(float)ib[l].x; h[1] = (__bf16)(float)ib[l].y;
            h[2] = (__bf16)(float)ib[l].z; h[3] = (__bf16)(float)ib[l].w;
            *reinterpret_cast<bf16x4*>(&sB[r * 32 + c4 * 4]) = h;
        }
        __syncthreads();

        bf16x8 af[4], bfr[4];
#pragma unroll
        for (int i = 0; i < 4; ++i)
            af[i] = *reinterpret_cast<const bf16x8*>(
                        &sA[(wm + i * 16 + lm) * 32 + kq * 8]);
#pragma unroll
        for (int j = 0; j < 4; ++j)
            bfr[j] = *reinterpret_cast<const bf16x8*>(
                        &sB[(wn + j * 16 + lm) * 32 + kq * 8]);
#pragma unroll
        for (int i = 0; i < 4; ++i)
#pragma unroll
            for (int j = 0; j < 4; ++j)
                acc[i][j] = __builtin_amdgcn_mfma_f32_16x16x32_bf16(
                                af[i], bfr[j], acc[i][j], 0, 0, 0);
    }

#pragma unroll
    for (int j = 0; j < 4; ++j) {
        int n = col0 + wn + j * 16 + lm;
        float sc = scale[n];
        float bi = bias[n];
#pragma unroll
        for (int i = 0; i < 4; ++i) {
#pragma unroll
            for (int r = 0; r < 4; ++r) {
                int m = row0 + wm + i * 16 + kq * 4 + r;
                Out[(size_t)m * N + n] = sc * acc[i][j][r] + bi;
            }
        }
    }
}

extern "C" void kernel_launch(void* const* d_in, const int* in_sizes, int n_in,
                              void* d_out, int out_size, void* d_ws, size_t ws_size,
                              hipStream_t stream) {
    const float* x     = (const float*)d_in[0];
    const int*   wq    = (const int*)d_in[1];
    const float* scale = (const float*)d_in[2];
    const float* bias  = (const float*)d_in[3];
    float* out = (float*)d_out;

    const int N = in_sizes[2];            // OUT = 4096
    const int K = in_sizes[1] / N;        // IN  = 4096
    const int M = in_sizes[0] / K;        // B*S = 8192

    const size_t xElems = (size_t)M * K;
    const size_t wElems = (size_t)N * K;
    const size_t need   = (xElems + wElems) * sizeof(__bf16);

    const bool cvt_ok = (ws_size >= need) && (xElems % 8 == 0) && (wElems % 8 == 0);
    const int  nt     = K / BK2;
    const bool gemm_ok = (M % BM2 == 0) && (N % BN2 == 0) && (K % BK2 == 0) &&
                         (nt % 2 == 0) && (nt >= 4);

    if (cvt_ok && gemm_ok) {
        __bf16* xb = (__bf16*)d_ws;
        __bf16* wb = xb + xElems;
        int nx8 = (int)(xElems / 8);
        int nw8 = (int)(wElems / 8);
        int total = nx8 + nw8;
        int cvtBlocks = (total + 255) / 256;
        if (cvtBlocks > 2048) cvtBlocks = 2048;
        hipLaunchKernelGGL(cvt_both8, dim3(cvtBlocks), dim3(256), 0, stream,
                           x, wq, xb, wb, nx8, nw8);
        hipLaunchKernelGGL(gemm_bf16_bt_8ph, dim3(N / BN2, M / BM2), dim3(512),
                           0, stream, xb, wb, scale, bias, out, M, N, K);
        return;
    }

    hipLaunchKernelGGL(fp4linear_gemm, dim3(N / BN, M / BM), dim3(256), 0, stream,
                       x, wq, scale, bias, out, M, N, K);
}